// Round 19
// baseline (130.239 us; speedup 1.0000x reference)
//
#include <hip/hip_runtime.h>
#include <hip/hip_bf16.h>

#define B_  8
#define T_  2048
#define C_  1024
#define H_  128

using f32x4  = __attribute__((ext_vector_type(4))) float;
using f32x16 = __attribute__((ext_vector_type(16))) float;
using bf16x8 = __attribute__((ext_vector_type(8))) short;

__device__ __forceinline__ unsigned short f2bf(float f) {
    union { float f; unsigned u; } v; v.f = f;
    unsigned r = v.u + 0x7FFFu + ((v.u >> 16) & 1u);   // RNE
    return (unsigned short)(r >> 16);
}
__device__ __forceinline__ float bf2f(unsigned short s) {
    union { unsigned u; float f; } v; v.u = ((unsigned)s) << 16;
    return v.f;
}

// lgkm-only barrier: LDS visibility; register-staged global loads stay in flight
#define BAR() do { asm volatile("s_waitcnt lgkmcnt(0)" ::: "memory"); \
                   __builtin_amdgcn_s_barrier(); } while (0)

// DPP cross-lane reduce within 16-lane rows (VALU-speed)
template<int C>
__device__ __forceinline__ float dppf(float v) {
    return __int_as_float(__builtin_amdgcn_update_dpp(0, __float_as_int(v), C, 0xF, 0xF, true));
}
#define DPPRED_MAX(v) { v = fmaxf(v, dppf<0xB1>(v)); v = fmaxf(v, dppf<0x4E>(v)); \
                        v = fmaxf(v, dppf<0x141>(v)); v = fmaxf(v, dppf<0x140>(v)); }
#define DPPRED_SUM(v) { v = v + dppf<0xB1>(v); v = v + dppf<0x4E>(v); \
                        v = v + dppf<0x141>(v); v = v + dppf<0x140>(v); }

// ---------------------------------------------------------------------------
// W{q,k,v} fp32 [1024][128] -> Wt K-TILED bf16: Wt[k>>5][col][k&31]
// (each 384x32 B-tile = contiguous 24 KB stream). Wq pre-scaled 1/32.
// ---------------------------------------------------------------------------
__global__ void wconv_kernel(const float* __restrict__ Wq,
                             const float* __restrict__ Wk,
                             const float* __restrict__ Wv,
                             unsigned short* __restrict__ Wt) {
    int id  = blockIdx.x * 256 + threadIdx.x;
    int col = id % 384;
    int k   = id / 384;
    const float* W = (col < 128) ? Wq : ((col < 256) ? Wk : Wv);
    float v = W[k * H_ + (col & 127)];
    if (col < 128) v *= 0.03125f;   // fold C^-0.5 into Wq (exact pow2)
    Wt[(size_t)(k >> 5) * 12288 + col * 32 + (k & 31)] = f2bf(v);
}

// ---------------------------------------------------------------------------
// Fused projection GEMM — 4 waves of 64r x 96c (acc[2][3] f32x16), 256 blocks
// x 256 thr. Frag-read count per block-step: 4 waves x (2 af + 3 bf) x 2 kh
// = 40 b128 (was 64 with 8x 32x96 waves) and half the waves contend for the
// LDS pipe — attacks the measured LDS-issue bound (~1470 cy/CU-step).
// Same proven skeleton: BK=32, k-tiled Wt, padded [*][36] LDS, lgkm-only BAR,
// x 3-deep reg prefetch, B 1-step reg prefetch.
// ---------------------------------------------------------------------------
__launch_bounds__(256, 1)
__global__ void gemm_kernel(const float* __restrict__ x,
                            const unsigned short* __restrict__ Wt,
                            unsigned short* __restrict__ qb,
                            unsigned short* __restrict__ kb,
                            unsigned short* __restrict__ vT) {
    __shared__ unsigned short Bs[2][13824];   // [384 col][36], pad 32->36
    __shared__ unsigned short As[2][2304];    // [64 row][36]

    const int tid  = threadIdx.x;
    const int wave = tid >> 6;
    const int lane = tid & 63;
    const int r32 = lane & 31, hi32 = lane >> 5;
    const int row0  = blockIdx.x * 64;
    const int wcol0 = wave * 96;              // wave col panel; rows: all 64

    // A staging: thread -> (row = tid>>2, 8 fp32 at (tid&3)*8)
    const int arow = tid >> 2;
    const int aq8  = (tid & 3) * 8;
    const float* xsrc = x + (size_t)(row0 + arow) * C_ + aq8;

    // B staging: 6 x 16B chunks; chunk = tid + j*256 -> col=chunk>>2, sub=chunk&3
    const unsigned short* bsrc = Wt + (size_t)tid * 8;

    f32x16 acc[2][3];
    #pragma unroll
    for (int rt = 0; rt < 2; ++rt)
        #pragma unroll
        for (int ct = 0; ct < 3; ++ct)
            #pragma unroll
            for (int e = 0; e < 16; ++e) acc[rt][ct][e] = 0.f;

    // prologue: stage step 0 directly; x(1), x(2) into regs
    {
        #pragma unroll
        for (int j = 0; j < 6; ++j) {
            const int chunk = tid + j * 256;
            *(uint4*)&Bs[0][(chunk >> 2) * 36 + (chunk & 3) * 8] =
                *(const uint4*)(bsrc + j * 2048);
        }
        float4 f0 = *(const float4*)(xsrc);
        float4 f1 = *(const float4*)(xsrc + 4);
        unsigned a0 = f2bf(f0.x) | ((unsigned)f2bf(f0.y) << 16);
        unsigned a1 = f2bf(f0.z) | ((unsigned)f2bf(f0.w) << 16);
        unsigned a2 = f2bf(f1.x) | ((unsigned)f2bf(f1.y) << 16);
        unsigned a3 = f2bf(f1.z) | ((unsigned)f2bf(f1.w) << 16);
        *(uint4*)&As[0][arow * 36 + aq8] = uint4{a0, a1, a2, a3};
    }
    float4 hA0 = *(const float4*)(xsrc + 32);
    float4 hA1 = *(const float4*)(xsrc + 36);
    float4 hB0 = *(const float4*)(xsrc + 64);
    float4 hB1 = *(const float4*)(xsrc + 68);
    BAR();

    for (int k = 0; k < 32; ++k) {
        const int cur = k & 1, nxt = cur ^ 1;

        // issue B(k+1) (L2) and x(k+3) (HBM, 3-deep) loads
        uint4 br[6];
        if (k < 31) {
            const unsigned short* g = bsrc + (size_t)(k + 1) * 12288;
            #pragma unroll
            for (int j = 0; j < 6; ++j) br[j] = *(const uint4*)(g + j * 2048);
        }
        const int kn = (k + 3 < 31) ? k + 3 : 31;
        float4 xf0 = *(const float4*)(xsrc + kn * 32);
        float4 xf1 = *(const float4*)(xsrc + kn * 32 + 4);

        // MFMA: 2 k-halves x (2 row-tiles x 3 col-tiles) of 32
        #pragma unroll
        for (int kh = 0; kh < 2; ++kh) {
            const int kofs = kh * 16 + 8 * hi32;
            bf16x8 af[2];
            #pragma unroll
            for (int rt = 0; rt < 2; ++rt)
                af[rt] = *(const bf16x8*)&As[cur][(rt * 32 + r32) * 36 + kofs];
            #pragma unroll
            for (int ct = 0; ct < 3; ++ct) {
                bf16x8 bf = *(const bf16x8*)&Bs[cur][(wcol0 + ct * 32 + r32) * 36 + kofs];
                #pragma unroll
                for (int rt = 0; rt < 2; ++rt)
                    acc[rt][ct] = __builtin_amdgcn_mfma_f32_32x32x16_bf16(af[rt], bf, acc[rt][ct], 0, 0, 0);
            }
        }

        // write step k+1 buffers (B from this step's L2 loads; A from 3-deep x)
        if (k < 31) {
            #pragma unroll
            for (int j = 0; j < 6; ++j) {
                const int chunk = tid + j * 256;
                *(uint4*)&Bs[nxt][(chunk >> 2) * 36 + (chunk & 3) * 8] = br[j];
            }
            unsigned a0 = f2bf(hA0.x) | ((unsigned)f2bf(hA0.y) << 16);
            unsigned a1 = f2bf(hA0.z) | ((unsigned)f2bf(hA0.w) << 16);
            unsigned a2 = f2bf(hA1.x) | ((unsigned)f2bf(hA1.y) << 16);
            unsigned a3 = f2bf(hA1.z) | ((unsigned)f2bf(hA1.w) << 16);
            *(uint4*)&As[nxt][arow * 36 + aq8] = uint4{a0, a1, a2, a3};
        }
        BAR();
        hA0 = hB0; hA1 = hB1; hB0 = xf0; hB1 = xf1;
    }

    // epilogue: C/D col = lane&31, row = (reg&3) + 8*(reg>>2) + 4*(lane>>5)
    #pragma unroll
    for (int rt = 0; rt < 2; ++rt) {
        #pragma unroll
        for (int ct = 0; ct < 3; ++ct) {
            int col = wcol0 + ct * 32 + r32;
            int head = col >> 7;
            int h = col & 127;
            #pragma unroll
            for (int reg = 0; reg < 16; ++reg) {
                int rg = row0 + rt * 32 + (reg & 3) + 8 * (reg >> 2) + 4 * hi32;
                unsigned short val = f2bf(acc[rt][ct][reg]);
                if (head == 0)      qb[(size_t)rg * H_ + h] = val;
                else if (head == 1) kb[(size_t)rg * H_ + h] = val;
                else {
                    int b = rg >> 11, t = rg & (T_ - 1);
                    vT[((size_t)b * H_ + h) * T_ + t] = val;
                }
            }
        }
    }
}

// ---------------------------------------------------------------------------
// Flash pass 1 — R18-exact (proven best). chunk = 256 kv = 4 x KV64, grid 512,
// double-buffered K/V LDS, one lgkm barrier per tile, bf16 O partials.
// ---------------------------------------------------------------------------
__launch_bounds__(512, 2)
__global__ void attn1_kernel(const unsigned short* __restrict__ qb,
                             const unsigned short* __restrict__ kb,
                             const unsigned short* __restrict__ vT,
                             unsigned short* __restrict__ Opart,
                             float* __restrict__ MLpart) {
    __shared__ unsigned short Ks[2][64 * 128];   // [buf][kv][k], XOR-swizzled
    __shared__ unsigned short Vs[2][128 * 64];   // [buf][h][kv], swizzled
    __shared__ unsigned short Ps[8][16][72];     // per-wave P transpose

    const int tid  = threadIdx.x;
    const int wave = tid >> 6;
    const int lane = tid & 63;
    const int lo = lane & 15, hi = lane >> 4;

    const int bid   = blockIdx.x;
    const int b     = bid & 7;
    const int chunk = (bid >> 3) & 7;
    const int qt    = 7 - (bid >> 6);
    if (chunk > qt) return;

    const int kv_begin = chunk << 8;
    const size_t bT = (size_t)b * T_;
    const int qrow0 = (qt << 8) + wave * 32;

    const int krow = tid >> 3, kcol = (tid & 7) * 2;
    const int vrow = tid >> 2, vcol = (tid & 3) * 2;
    const unsigned short* kgsrc = kb + (bT + krow) * H_ + kcol * 8;
    const unsigned short* vgsrc = vT + ((size_t)b * H_ + vrow) * T_ + vcol * 8;
    const int koff0 = krow * 128 + ((kcol ^ (krow & 7)) * 8);
    const int koff1 = krow * 128 + (((kcol + 1) ^ (krow & 7)) * 8);
    const int voff0 = vrow * 64 + ((vcol ^ (vrow & 7)) * 8);
    const int voff1 = vrow * 64 + (((vcol + 1) ^ (vrow & 7)) * 8);

    bf16x8 qf[2][4];
    #pragma unroll
    for (int q2 = 0; q2 < 2; ++q2)
        #pragma unroll
        for (int kc = 0; kc < 4; ++kc)
            qf[q2][kc] = *(const bf16x8*)(qb + (bT + qrow0 + 16 * q2 + lo) * H_ + kc * 32 + 8 * hi);

    float m[2][4], l[2][4];
    f32x4 o[2][8];
    #pragma unroll
    for (int q2 = 0; q2 < 2; ++q2)
        #pragma unroll
        for (int r = 0; r < 4; ++r) { m[q2][r] = -1e30f; l[q2][r] = 0.f; }
    #pragma unroll
    for (int q2 = 0; q2 < 2; ++q2)
        #pragma unroll
        for (int ct = 0; ct < 8; ++ct) o[q2][ct] = f32x4{0.f, 0.f, 0.f, 0.f};

    {
        uint4 a = *(const uint4*)(kgsrc + (size_t)kv_begin * H_);
        uint4 c = *(const uint4*)(kgsrc + (size_t)kv_begin * H_ + 8);
        uint4 d = *(const uint4*)(vgsrc + kv_begin);
        uint4 e = *(const uint4*)(vgsrc + kv_begin + 8);
        *(uint4*)&Ks[0][koff0] = a;
        *(uint4*)&Ks[0][koff1] = c;
        *(uint4*)&Vs[0][voff0] = d;
        *(uint4*)&Vs[0][voff1] = e;
    }
    uint4 kr0 = *(const uint4*)(kgsrc + (size_t)(kv_begin + 64) * H_);
    uint4 kr1 = *(const uint4*)(kgsrc + (size_t)(kv_begin + 64) * H_ + 8);
    uint4 vr0 = *(const uint4*)(vgsrc + kv_begin + 64);
    uint4 vr1 = *(const uint4*)(vgsrc + kv_begin + 64 + 8);
    BAR();

    for (int t = 0; t < 4; ++t) {
        const int cur = t & 1;
        const int kv0 = kv_begin + t * 64;

        if (kv0 <= qrow0 + 31) {
            f32x4 s[2][4];
            #pragma unroll
            for (int q2 = 0; q2 < 2; ++q2)
                #pragma unroll
                for (int ct4 = 0; ct4 < 4; ++ct4) s[q2][ct4] = f32x4{0.f, 0.f, 0.f, 0.f};
            __builtin_amdgcn_s_setprio(1);
            #pragma unroll
            for (int ct4 = 0; ct4 < 4; ++ct4) {
                const int row = ct4 * 16 + lo;
                #pragma unroll
                for (int kc = 0; kc < 4; ++kc) {
                    bf16x8 kf = *(const bf16x8*)&Ks[cur][row * 128 + (((kc * 4 + hi) ^ (row & 7)) * 8)];
                    s[0][ct4] = __builtin_amdgcn_mfma_f32_16x16x32_bf16(qf[0][kc], kf, s[0][ct4], 0, 0, 0);
                    s[1][ct4] = __builtin_amdgcn_mfma_f32_16x16x32_bf16(qf[1][kc], kf, s[1][ct4], 0, 0, 0);
                }
            }
            __builtin_amdgcn_s_setprio(0);

            if (kv0 + 63 >= qrow0) {
                #pragma unroll
                for (int q2 = 0; q2 < 2; ++q2)
                    #pragma unroll
                    for (int ct4 = 0; ct4 < 4; ++ct4)
                        #pragma unroll
                        for (int r = 0; r < 4; ++r)
                            if (kv0 + ct4 * 16 + lo > qrow0 + 16 * q2 + 4 * hi + r)
                                s[q2][ct4][r] = -1e30f;
            }

            float alpha[2][4];
            #pragma unroll
            for (int q2 = 0; q2 < 2; ++q2) {
                #pragma unroll
                for (int r = 0; r < 4; ++r) {
                    float pm = fmaxf(fmaxf(s[q2][0][r], s[q2][1][r]), fmaxf(s[q2][2][r], s[q2][3][r]));
                    DPPRED_MAX(pm);
                    float mn = fmaxf(m[q2][r], pm);
                    alpha[q2][r] = __expf(m[q2][r] - mn);
                    m[q2][r] = mn;
                    #pragma unroll
                    for (int ct4 = 0; ct4 < 4; ++ct4) s[q2][ct4][r] = __expf(s[q2][ct4][r] - mn);
                    float rs = (s[q2][0][r] + s[q2][1][r]) + (s[q2][2][r] + s[q2][3][r]);
                    DPPRED_SUM(rs);
                    l[q2][r] = l[q2][r] * alpha[q2][r] + rs;
                }
            }
            #pragma unroll
            for (int q2 = 0; q2 < 2; ++q2)
                #pragma unroll
                for (int ct = 0; ct < 8; ++ct)
                    #pragma unroll
                    for (int r = 0; r < 4; ++r) o[q2][ct][r] *= alpha[q2][r];

            bf16x8 pa[2][2];
            #pragma unroll
            for (int q2 = 0; q2 < 2; ++q2) {
                #pragma unroll
                for (int ct4 = 0; ct4 < 4; ++ct4)
                    #pragma unroll
                    for (int r = 0; r < 4; ++r)
                        Ps[wave][4 * hi + r][ct4 * 16 + lo] = f2bf(s[q2][ct4][r]);
                pa[q2][0] = *(const bf16x8*)&Ps[wave][lo][8 * hi];
                pa[q2][1] = *(const bf16x8*)&Ps[wave][lo][32 + 8 * hi];
            }

            __builtin_amdgcn_s_setprio(1);
            #pragma unroll
            for (int ct = 0; ct < 8; ++ct) {
                const int row = ct * 16 + lo;
                #pragma unroll
                for (int half = 0; half < 2; ++half) {
                    bf16x8 vf = *(const bf16x8*)&Vs[cur][row * 64 + (((half * 4 + hi) ^ (row & 7)) * 8)];
                    o[0][ct] = __builtin_amdgcn_mfma_f32_16x16x32_bf16(pa[0][half], vf, o[0][ct], 0, 0, 0);
                    o[1][ct] = __builtin_amdgcn_mfma_f32_16x16x32_bf16(pa[1][half], vf, o[1][ct], 0, 0, 0);
                }
            }
            __builtin_amdgcn_s_setprio(0);
        }

        if (t < 3) {
            *(uint4*)&Ks[cur ^ 1][koff0] = kr0;
            *(uint4*)&Ks[cur ^ 1][koff1] = kr1;
            *(uint4*)&Vs[cur ^ 1][voff0] = vr0;
            *(uint4*)&Vs[cur ^ 1][voff1] = vr1;
            if (t < 2) {
                const int kvn = kv_begin + (t + 2) * 64;
                kr0 = *(const uint4*)(kgsrc + (size_t)kvn * H_);
                kr1 = *(const uint4*)(kgsrc + (size_t)kvn * H_ + 8);
                vr0 = *(const uint4*)(vgsrc + kvn);
                vr1 = *(const uint4*)(vgsrc + kvn + 8);
            }
        }
        BAR();
    }

    const int slot = b * 36 + ((qt * (qt + 1)) >> 1) + chunk;
    unsigned short* op = Opart + (size_t)slot * 32768 + (size_t)(wave * 32) * 128;
    #pragma unroll
    for (int q2 = 0; q2 < 2; ++q2)
        #pragma unroll
        for (int ct = 0; ct < 8; ++ct)
            #pragma unroll
            for (int r = 0; r < 4; ++r)
                op[(16 * q2 + 4 * hi + r) * 128 + ct * 16 + lo] = f2bf(o[q2][ct][r]);
    if (lo == 0) {
        #pragma unroll
        for (int q2 = 0; q2 < 2; ++q2)
            #pragma unroll
            for (int r = 0; r < 4; ++r) {
                int base = slot * 512 + (wave * 32 + 16 * q2 + 4 * hi + r) * 2;
                MLpart[base]     = m[q2][r];
                MLpart[base + 1] = l[q2][r];
            }
    }
}

// ---------------------------------------------------------------------------
// Flash pass 2: merge <= 8 bf16 chunk partials. 512 blocks x 128 thr.
// ---------------------------------------------------------------------------
__launch_bounds__(128)
__global__ void attn2_kernel(const unsigned short* __restrict__ Opart,
                             const float* __restrict__ MLpart,
                             float* __restrict__ out) {
    const int bid = blockIdx.x;
    const int b   = bid & 7;
    const int qt  = (bid >> 3) & 7;
    const int sub = bid >> 6;              // 0..7
    const int nch = qt + 1;
    const int slot0 = b * 36 + ((qt * (qt + 1)) >> 1);

    const int tid  = threadIdx.x;
    const int row  = tid >> 2;             // 0..31
    const int h0   = (tid & 3) * 32;
    const int srow = sub * 32 + row;       // row within slot

    float M = -1e30f;
    for (int c = 0; c < nch; ++c)
        M = fmaxf(M, MLpart[(slot0 + c) * 512 + srow * 2]);
    float L = 0.f;
    for (int c = 0; c < nch; ++c) {
        float mc = MLpart[(slot0 + c) * 512 + srow * 2];
        float lc = MLpart[(slot0 + c) * 512 + srow * 2 + 1];
        L += lc * __expf(mc - M);
    }

    float accv[32];
    #pragma unroll
    for (int j = 0; j < 32; ++j) accv[j] = 0.f;
    for (int c = 0; c < nch; ++c) {
        float wc = __expf(MLpart[(slot0 + c) * 512 + srow * 2] - M);
        const unsigned short* src = Opart + (size_t)(slot0 + c) * 32768 + (size_t)srow * 128 + h0;
        #pragma unroll
        for (int j = 0; j < 4; ++j) {
            bf16x8 v = *(const bf16x8*)(src + j * 8);
            #pragma unroll
            for (int e = 0; e < 8; ++e)
                accv[j * 8 + e] += wc * bf2f((unsigned short)v[e]);
        }
    }
    float inv = 1.f / L;
    float4* dst = (float4*)(out + ((size_t)b * T_ + qt * 256 + srow) * H_ + h0);
    #pragma unroll
    for (int j = 0; j < 8; ++j)
        dst[j] = float4{accv[4 * j] * inv, accv[4 * j + 1] * inv,
                        accv[4 * j + 2] * inv, accv[4 * j + 3] * inv};
}

extern "C" void kernel_launch(void* const* d_in, const int* in_sizes, int n_in,
                              void* d_out, int out_size, void* d_ws, size_t ws_size,
                              hipStream_t stream) {
    const float* x  = (const float*)d_in[0];
    const float* Wq = (const float*)d_in[1];
    const float* Wk = (const float*)d_in[2];
    const float* Wv = (const float*)d_in[3];
    float* out = (float*)d_out;

    char* ws = (char*)d_ws;
    unsigned short* Wt  = (unsigned short*)ws;                          // 0.75 MB
    unsigned short* qbf = (unsigned short*)(ws + (size_t)384 * 1024 * 2);
    unsigned short* kbf = qbf + (size_t)B_ * T_ * H_;
    unsigned short* vTf = kbf + (size_t)B_ * T_ * H_;
    unsigned short* Opart = vTf + (size_t)B_ * T_ * H_;                 // 18 MB bf16
    float* MLpart = (float*)((char*)Opart + (size_t)288 * 32768 * 2);   // 0.56 MB

    wconv_kernel<<<(384 * 1024) / 256, 256, 0, stream>>>(Wq, Wk, Wv, Wt);
    gemm_kernel<<<B_ * T_ / 64, 256, 0, stream>>>(x, Wt, qbf, kbf, vTf);
    attn1_kernel<<<512, 512, 0, stream>>>(qbf, kbf, vTf, Opart, MLpart);
    attn2_kernel<<<512, 128, 0, stream>>>(Opart, MLpart, out);
}

// Round 20
// 92.645 us; speedup vs baseline: 1.4058x; 1.4058x over previous
//
#include <hip/hip_runtime.h>
#include <hip/hip_bf16.h>

#define B_  8
#define T_  2048
#define C_  1024
#define H_  128

using f32x4  = __attribute__((ext_vector_type(4))) float;
using f32x16 = __attribute__((ext_vector_type(16))) float;
using bf16x8 = __attribute__((ext_vector_type(8))) short;

__device__ __forceinline__ unsigned short f2bf(float f) {
    union { float f; unsigned u; } v; v.f = f;
    unsigned r = v.u + 0x7FFFu + ((v.u >> 16) & 1u);   // RNE
    return (unsigned short)(r >> 16);
}
__device__ __forceinline__ float bf2f(unsigned short s) {
    union { unsigned u; float f; } v; v.u = ((unsigned)s) << 16;
    return v.f;
}

// lgkm-only barrier: LDS visibility; register-staged global loads stay in flight
#define BAR() do { asm volatile("s_waitcnt lgkmcnt(0)" ::: "memory"); \
                   __builtin_amdgcn_s_barrier(); } while (0)

// DPP cross-lane reduce within 16-lane rows (VALU-speed)
template<int C>
__device__ __forceinline__ float dppf(float v) {
    return __int_as_float(__builtin_amdgcn_update_dpp(0, __float_as_int(v), C, 0xF, 0xF, true));
}
#define DPPRED_MAX(v) { v = fmaxf(v, dppf<0xB1>(v)); v = fmaxf(v, dppf<0x4E>(v)); \
                        v = fmaxf(v, dppf<0x141>(v)); v = fmaxf(v, dppf<0x140>(v)); }
#define DPPRED_SUM(v) { v = v + dppf<0xB1>(v); v = v + dppf<0x4E>(v); \
                        v = v + dppf<0x141>(v); v = v + dppf<0x140>(v); }

// ---------------------------------------------------------------------------
// W{q,k,v} fp32 [1024][128] -> Wt K-TILED bf16: Wt[k>>5][col][k&31]
// (each 384x32 B-tile = contiguous 24 KB stream). Wq pre-scaled 1/32.
// ---------------------------------------------------------------------------
__global__ void wconv_kernel(const float* __restrict__ Wq,
                             const float* __restrict__ Wk,
                             const float* __restrict__ Wv,
                             unsigned short* __restrict__ Wt) {
    int id  = blockIdx.x * 256 + threadIdx.x;
    int col = id % 384;
    int k   = id / 384;
    const float* W = (col < 128) ? Wq : ((col < 256) ? Wk : Wv);
    float v = W[k * H_ + (col & 127)];
    if (col < 128) v *= 0.03125f;   // fold C^-0.5 into Wq (exact pow2)
    Wt[(size_t)(k >> 5) * 12288 + col * 32 + (k & 31)] = f2bf(v);
}

// ---------------------------------------------------------------------------
// Fused projection GEMM — 6 waves (384 thr) of 64r x 64c (acc[2][2] f32x16),
// grid 256, tile 64x384, BK=32. 64x64 wave = optimal read:MFMA ratio:
// 8 b128 frag reads feed 8 MFMA (R15: 8 reads -> 6 MFMA). 2 blocks/CU =
// 12 waves/CU = 3/SIMD (TLP preserved, unlike R19's 1/SIMD failure).
// Same proven skeleton: k-tiled Wt stream, padded [*][36] LDS, lgkm-only
// BAR, x 3-deep reg prefetch (A-staging by tid<256 only), B 1-step prefetch.
// ---------------------------------------------------------------------------
__launch_bounds__(384, 2)
__global__ void gemm_kernel(const float* __restrict__ x,
                            const unsigned short* __restrict__ Wt,
                            unsigned short* __restrict__ qb,
                            unsigned short* __restrict__ kb,
                            unsigned short* __restrict__ vT) {
    __shared__ unsigned short Bs[2][13824];   // [384 col][36], pad 32->36
    __shared__ unsigned short As[2][2304];    // [64 row][36]

    const int tid  = threadIdx.x;
    const int wave = tid >> 6;                // 0..5
    const int lane = tid & 63;
    const int r32 = lane & 31, hi32 = lane >> 5;
    const int row0  = blockIdx.x * 64;
    const int wcol0 = wave * 64;              // wave col panel; rows: all 64

    // A staging (tid < 256 only): thread -> (row = tid>>2, 8 fp32 at (tid&3)*8)
    const bool astg = (tid < 256);
    const int arow = tid >> 2;                // 0..63 for tid<256
    const int aq8  = (tid & 3) * 8;
    const float* xsrc = x + (size_t)(row0 + (astg ? arow : 0)) * C_ + aq8;

    // B staging: 4 x 16B chunks; chunk = tid + j*384 -> col=chunk>>2, sub=chunk&3
    const unsigned short* bsrc = Wt + (size_t)tid * 8;

    f32x16 acc[2][2];
    #pragma unroll
    for (int rt = 0; rt < 2; ++rt)
        #pragma unroll
        for (int ct = 0; ct < 2; ++ct)
            #pragma unroll
            for (int e = 0; e < 16; ++e) acc[rt][ct][e] = 0.f;

    // prologue: stage step 0 directly; x(1), x(2) into regs
    {
        #pragma unroll
        for (int j = 0; j < 4; ++j) {
            const int chunk = tid + j * 384;
            *(uint4*)&Bs[0][(chunk >> 2) * 36 + (chunk & 3) * 8] =
                *(const uint4*)(bsrc + j * 3072);
        }
        if (astg) {
            float4 f0 = *(const float4*)(xsrc);
            float4 f1 = *(const float4*)(xsrc + 4);
            unsigned a0 = f2bf(f0.x) | ((unsigned)f2bf(f0.y) << 16);
            unsigned a1 = f2bf(f0.z) | ((unsigned)f2bf(f0.w) << 16);
            unsigned a2 = f2bf(f1.x) | ((unsigned)f2bf(f1.y) << 16);
            unsigned a3 = f2bf(f1.z) | ((unsigned)f2bf(f1.w) << 16);
            *(uint4*)&As[0][arow * 36 + aq8] = uint4{a0, a1, a2, a3};
        }
    }
    float4 hA0, hA1, hB0, hB1;
    if (astg) {
        hA0 = *(const float4*)(xsrc + 32);
        hA1 = *(const float4*)(xsrc + 36);
        hB0 = *(const float4*)(xsrc + 64);
        hB1 = *(const float4*)(xsrc + 68);
    }
    BAR();

    for (int k = 0; k < 32; ++k) {
        const int cur = k & 1, nxt = cur ^ 1;

        // issue B(k+1) (L2) and x(k+3) (HBM, 3-deep) loads
        uint4 br[4];
        if (k < 31) {
            const unsigned short* g = bsrc + (size_t)(k + 1) * 12288;
            #pragma unroll
            for (int j = 0; j < 4; ++j) br[j] = *(const uint4*)(g + j * 3072);
        }
        float4 xf0, xf1;
        if (astg) {
            const int kn = (k + 3 < 31) ? k + 3 : 31;
            xf0 = *(const float4*)(xsrc + kn * 32);
            xf1 = *(const float4*)(xsrc + kn * 32 + 4);
        }

        // MFMA: 2 k-halves x (2 row-tiles x 2 col-tiles) of 32
        #pragma unroll
        for (int kh = 0; kh < 2; ++kh) {
            const int kofs = kh * 16 + 8 * hi32;
            bf16x8 af[2];
            #pragma unroll
            for (int rt = 0; rt < 2; ++rt)
                af[rt] = *(const bf16x8*)&As[cur][(rt * 32 + r32) * 36 + kofs];
            #pragma unroll
            for (int ct = 0; ct < 2; ++ct) {
                bf16x8 bf = *(const bf16x8*)&Bs[cur][(wcol0 + ct * 32 + r32) * 36 + kofs];
                #pragma unroll
                for (int rt = 0; rt < 2; ++rt)
                    acc[rt][ct] = __builtin_amdgcn_mfma_f32_32x32x16_bf16(af[rt], bf, acc[rt][ct], 0, 0, 0);
            }
        }

        // write step k+1 buffers (B from this step's L2 loads; A from 3-deep x)
        if (k < 31) {
            #pragma unroll
            for (int j = 0; j < 4; ++j) {
                const int chunk = tid + j * 384;
                *(uint4*)&Bs[nxt][(chunk >> 2) * 36 + (chunk & 3) * 8] = br[j];
            }
            if (astg) {
                unsigned a0 = f2bf(hA0.x) | ((unsigned)f2bf(hA0.y) << 16);
                unsigned a1 = f2bf(hA0.z) | ((unsigned)f2bf(hA0.w) << 16);
                unsigned a2 = f2bf(hA1.x) | ((unsigned)f2bf(hA1.y) << 16);
                unsigned a3 = f2bf(hA1.z) | ((unsigned)f2bf(hA1.w) << 16);
                *(uint4*)&As[nxt][arow * 36 + aq8] = uint4{a0, a1, a2, a3};
            }
        }
        BAR();
        if (astg) { hA0 = hB0; hA1 = hB1; hB0 = xf0; hB1 = xf1; }
    }

    // epilogue: C/D col = lane&31, row = (reg&3) + 8*(reg>>2) + 4*(lane>>5)
    #pragma unroll
    for (int rt = 0; rt < 2; ++rt) {
        #pragma unroll
        for (int ct = 0; ct < 2; ++ct) {
            int col = wcol0 + ct * 32 + r32;
            int head = col >> 7;
            int h = col & 127;
            #pragma unroll
            for (int reg = 0; reg < 16; ++reg) {
                int rg = row0 + rt * 32 + (reg & 3) + 8 * (reg >> 2) + 4 * hi32;
                unsigned short val = f2bf(acc[rt][ct][reg]);
                if (head == 0)      qb[(size_t)rg * H_ + h] = val;
                else if (head == 1) kb[(size_t)rg * H_ + h] = val;
                else {
                    int b = rg >> 11, t = rg & (T_ - 1);
                    vT[((size_t)b * H_ + h) * T_ + t] = val;
                }
            }
        }
    }
}

// ---------------------------------------------------------------------------
// Flash pass 1 — R18-exact (proven best). chunk = 256 kv = 4 x KV64, grid 512,
// double-buffered K/V LDS, one lgkm barrier per tile, bf16 O partials.
// ---------------------------------------------------------------------------
__launch_bounds__(512, 2)
__global__ void attn1_kernel(const unsigned short* __restrict__ qb,
                             const unsigned short* __restrict__ kb,
                             const unsigned short* __restrict__ vT,
                             unsigned short* __restrict__ Opart,
                             float* __restrict__ MLpart) {
    __shared__ unsigned short Ks[2][64 * 128];   // [buf][kv][k], XOR-swizzled
    __shared__ unsigned short Vs[2][128 * 64];   // [buf][h][kv], swizzled
    __shared__ unsigned short Ps[8][16][72];     // per-wave P transpose

    const int tid  = threadIdx.x;
    const int wave = tid >> 6;
    const int lane = tid & 63;
    const int lo = lane & 15, hi = lane >> 4;

    const int bid   = blockIdx.x;
    const int b     = bid & 7;
    const int chunk = (bid >> 3) & 7;
    const int qt    = 7 - (bid >> 6);
    if (chunk > qt) return;

    const int kv_begin = chunk << 8;
    const size_t bT = (size_t)b * T_;
    const int qrow0 = (qt << 8) + wave * 32;

    const int krow = tid >> 3, kcol = (tid & 7) * 2;
    const int vrow = tid >> 2, vcol = (tid & 3) * 2;
    const unsigned short* kgsrc = kb + (bT + krow) * H_ + kcol * 8;
    const unsigned short* vgsrc = vT + ((size_t)b * H_ + vrow) * T_ + vcol * 8;
    const int koff0 = krow * 128 + ((kcol ^ (krow & 7)) * 8);
    const int koff1 = krow * 128 + (((kcol + 1) ^ (krow & 7)) * 8);
    const int voff0 = vrow * 64 + ((vcol ^ (vrow & 7)) * 8);
    const int voff1 = vrow * 64 + (((vcol + 1) ^ (vrow & 7)) * 8);

    bf16x8 qf[2][4];
    #pragma unroll
    for (int q2 = 0; q2 < 2; ++q2)
        #pragma unroll
        for (int kc = 0; kc < 4; ++kc)
            qf[q2][kc] = *(const bf16x8*)(qb + (bT + qrow0 + 16 * q2 + lo) * H_ + kc * 32 + 8 * hi);

    float m[2][4], l[2][4];
    f32x4 o[2][8];
    #pragma unroll
    for (int q2 = 0; q2 < 2; ++q2)
        #pragma unroll
        for (int r = 0; r < 4; ++r) { m[q2][r] = -1e30f; l[q2][r] = 0.f; }
    #pragma unroll
    for (int q2 = 0; q2 < 2; ++q2)
        #pragma unroll
        for (int ct = 0; ct < 8; ++ct) o[q2][ct] = f32x4{0.f, 0.f, 0.f, 0.f};

    {
        uint4 a = *(const uint4*)(kgsrc + (size_t)kv_begin * H_);
        uint4 c = *(const uint4*)(kgsrc + (size_t)kv_begin * H_ + 8);
        uint4 d = *(const uint4*)(vgsrc + kv_begin);
        uint4 e = *(const uint4*)(vgsrc + kv_begin + 8);
        *(uint4*)&Ks[0][koff0] = a;
        *(uint4*)&Ks[0][koff1] = c;
        *(uint4*)&Vs[0][voff0] = d;
        *(uint4*)&Vs[0][voff1] = e;
    }
    uint4 kr0 = *(const uint4*)(kgsrc + (size_t)(kv_begin + 64) * H_);
    uint4 kr1 = *(const uint4*)(kgsrc + (size_t)(kv_begin + 64) * H_ + 8);
    uint4 vr0 = *(const uint4*)(vgsrc + kv_begin + 64);
    uint4 vr1 = *(const uint4*)(vgsrc + kv_begin + 64 + 8);
    BAR();

    for (int t = 0; t < 4; ++t) {
        const int cur = t & 1;
        const int kv0 = kv_begin + t * 64;

        if (kv0 <= qrow0 + 31) {
            f32x4 s[2][4];
            #pragma unroll
            for (int q2 = 0; q2 < 2; ++q2)
                #pragma unroll
                for (int ct4 = 0; ct4 < 4; ++ct4) s[q2][ct4] = f32x4{0.f, 0.f, 0.f, 0.f};
            __builtin_amdgcn_s_setprio(1);
            #pragma unroll
            for (int ct4 = 0; ct4 < 4; ++ct4) {
                const int row = ct4 * 16 + lo;
                #pragma unroll
                for (int kc = 0; kc < 4; ++kc) {
                    bf16x8 kf = *(const bf16x8*)&Ks[cur][row * 128 + (((kc * 4 + hi) ^ (row & 7)) * 8)];
                    s[0][ct4] = __builtin_amdgcn_mfma_f32_16x16x32_bf16(qf[0][kc], kf, s[0][ct4], 0, 0, 0);
                    s[1][ct4] = __builtin_amdgcn_mfma_f32_16x16x32_bf16(qf[1][kc], kf, s[1][ct4], 0, 0, 0);
                }
            }
            __builtin_amdgcn_s_setprio(0);

            if (kv0 + 63 >= qrow0) {
                #pragma unroll
                for (int q2 = 0; q2 < 2; ++q2)
                    #pragma unroll
                    for (int ct4 = 0; ct4 < 4; ++ct4)
                        #pragma unroll
                        for (int r = 0; r < 4; ++r)
                            if (kv0 + ct4 * 16 + lo > qrow0 + 16 * q2 + 4 * hi + r)
                                s[q2][ct4][r] = -1e30f;
            }

            float alpha[2][4];
            #pragma unroll
            for (int q2 = 0; q2 < 2; ++q2) {
                #pragma unroll
                for (int r = 0; r < 4; ++r) {
                    float pm = fmaxf(fmaxf(s[q2][0][r], s[q2][1][r]), fmaxf(s[q2][2][r], s[q2][3][r]));
                    DPPRED_MAX(pm);
                    float mn = fmaxf(m[q2][r], pm);
                    alpha[q2][r] = __expf(m[q2][r] - mn);
                    m[q2][r] = mn;
                    #pragma unroll
                    for (int ct4 = 0; ct4 < 4; ++ct4) s[q2][ct4][r] = __expf(s[q2][ct4][r] - mn);
                    float rs = (s[q2][0][r] + s[q2][1][r]) + (s[q2][2][r] + s[q2][3][r]);
                    DPPRED_SUM(rs);
                    l[q2][r] = l[q2][r] * alpha[q2][r] + rs;
                }
            }
            #pragma unroll
            for (int q2 = 0; q2 < 2; ++q2)
                #pragma unroll
                for (int ct = 0; ct < 8; ++ct)
                    #pragma unroll
                    for (int r = 0; r < 4; ++r) o[q2][ct][r] *= alpha[q2][r];

            bf16x8 pa[2][2];
            #pragma unroll
            for (int q2 = 0; q2 < 2; ++q2) {
                #pragma unroll
                for (int ct4 = 0; ct4 < 4; ++ct4)
                    #pragma unroll
                    for (int r = 0; r < 4; ++r)
                        Ps[wave][4 * hi + r][ct4 * 16 + lo] = f2bf(s[q2][ct4][r]);
                pa[q2][0] = *(const bf16x8*)&Ps[wave][lo][8 * hi];
                pa[q2][1] = *(const bf16x8*)&Ps[wave][lo][32 + 8 * hi];
            }

            __builtin_amdgcn_s_setprio(1);
            #pragma unroll
            for (int ct = 0; ct < 8; ++ct) {
                const int row = ct * 16 + lo;
                #pragma unroll
                for (int half = 0; half < 2; ++half) {
                    bf16x8 vf = *(const bf16x8*)&Vs[cur][row * 64 + (((half * 4 + hi) ^ (row & 7)) * 8)];
                    o[0][ct] = __builtin_amdgcn_mfma_f32_16x16x32_bf16(pa[0][half], vf, o[0][ct], 0, 0, 0);
                    o[1][ct] = __builtin_amdgcn_mfma_f32_16x16x32_bf16(pa[1][half], vf, o[1][ct], 0, 0, 0);
                }
            }
            __builtin_amdgcn_s_setprio(0);
        }

        if (t < 3) {
            *(uint4*)&Ks[cur ^ 1][koff0] = kr0;
            *(uint4*)&Ks[cur ^ 1][koff1] = kr1;
            *(uint4*)&Vs[cur ^ 1][voff0] = vr0;
            *(uint4*)&Vs[cur ^ 1][voff1] = vr1;
            if (t < 2) {
                const int kvn = kv_begin + (t + 2) * 64;
                kr0 = *(const uint4*)(kgsrc + (size_t)kvn * H_);
                kr1 = *(const uint4*)(kgsrc + (size_t)kvn * H_ + 8);
                vr0 = *(const uint4*)(vgsrc + kvn);
                vr1 = *(const uint4*)(vgsrc + kvn + 8);
            }
        }
        BAR();
    }

    const int slot = b * 36 + ((qt * (qt + 1)) >> 1) + chunk;
    unsigned short* op = Opart + (size_t)slot * 32768 + (size_t)(wave * 32) * 128;
    #pragma unroll
    for (int q2 = 0; q2 < 2; ++q2)
        #pragma unroll
        for (int ct = 0; ct < 8; ++ct)
            #pragma unroll
            for (int r = 0; r < 4; ++r)
                op[(16 * q2 + 4 * hi + r) * 128 + ct * 16 + lo] = f2bf(o[q2][ct][r]);
    if (lo == 0) {
        #pragma unroll
        for (int q2 = 0; q2 < 2; ++q2)
            #pragma unroll
            for (int r = 0; r < 4; ++r) {
                int base = slot * 512 + (wave * 32 + 16 * q2 + 4 * hi + r) * 2;
                MLpart[base]     = m[q2][r];
                MLpart[base + 1] = l[q2][r];
            }
    }
}

// ---------------------------------------------------------------------------
// Flash pass 2: merge <= 8 bf16 chunk partials. 512 blocks x 128 thr.
// ---------------------------------------------------------------------------
__launch_bounds__(128)
__global__ void attn2_kernel(const unsigned short* __restrict__ Opart,
                             const float* __restrict__ MLpart,
                             float* __restrict__ out) {
    const int bid = blockIdx.x;
    const int b   = bid & 7;
    const int qt  = (bid >> 3) & 7;
    const int sub = bid >> 6;              // 0..7
    const int nch = qt + 1;
    const int slot0 = b * 36 + ((qt * (qt + 1)) >> 1);

    const int tid  = threadIdx.x;
    const int row  = tid >> 2;             // 0..31
    const int h0   = (tid & 3) * 32;
    const int srow = sub * 32 + row;       // row within slot

    float M = -1e30f;
    for (int c = 0; c < nch; ++c)
        M = fmaxf(M, MLpart[(slot0 + c) * 512 + srow * 2]);
    float L = 0.f;
    for (int c = 0; c < nch; ++c) {
        float mc = MLpart[(slot0 + c) * 512 + srow * 2];
        float lc = MLpart[(slot0 + c) * 512 + srow * 2 + 1];
        L += lc * __expf(mc - M);
    }

    float accv[32];
    #pragma unroll
    for (int j = 0; j < 32; ++j) accv[j] = 0.f;
    for (int c = 0; c < nch; ++c) {
        float wc = __expf(MLpart[(slot0 + c) * 512 + srow * 2] - M);
        const unsigned short* src = Opart + (size_t)(slot0 + c) * 32768 + (size_t)srow * 128 + h0;
        #pragma unroll
        for (int j = 0; j < 4; ++j) {
            bf16x8 v = *(const bf16x8*)(src + j * 8);
            #pragma unroll
            for (int e = 0; e < 8; ++e)
                accv[j * 8 + e] += wc * bf2f((unsigned short)v[e]);
        }
    }
    float inv = 1.f / L;
    float4* dst = (float4*)(out + ((size_t)b * T_ + qt * 256 + srow) * H_ + h0);
    #pragma unroll
    for (int j = 0; j < 8; ++j)
        dst[j] = float4{accv[4 * j] * inv, accv[4 * j + 1] * inv,
                        accv[4 * j + 2] * inv, accv[4 * j + 3] * inv};
}

extern "C" void kernel_launch(void* const* d_in, const int* in_sizes, int n_in,
                              void* d_out, int out_size, void* d_ws, size_t ws_size,
                              hipStream_t stream) {
    const float* x  = (const float*)d_in[0];
    const float* Wq = (const float*)d_in[1];
    const float* Wk = (const float*)d_in[2];
    const float* Wv = (const float*)d_in[3];
    float* out = (float*)d_out;

    char* ws = (char*)d_ws;
    unsigned short* Wt  = (unsigned short*)ws;                          // 0.75 MB
    unsigned short* qbf = (unsigned short*)(ws + (size_t)384 * 1024 * 2);
    unsigned short* kbf = qbf + (size_t)B_ * T_ * H_;
    unsigned short* vTf = kbf + (size_t)B_ * T_ * H_;
    unsigned short* Opart = vTf + (size_t)B_ * T_ * H_;                 // 18 MB bf16
    float* MLpart = (float*)((char*)Opart + (size_t)288 * 32768 * 2);   // 0.56 MB

    wconv_kernel<<<(384 * 1024) / 256, 256, 0, stream>>>(Wq, Wk, Wv, Wt);
    gemm_kernel<<<B_ * T_ / 64, 384, 0, stream>>>(x, Wt, qbf, kbf, vTf);
    attn1_kernel<<<512, 512, 0, stream>>>(qbf, kbf, vTf, Opart, MLpart);
    attn2_kernel<<<512, 128, 0, stream>>>(Opart, MLpart, out);
}